// Round 4
// baseline (419.612 us; speedup 1.0000x reference)
//
#include <hip/hip_runtime.h>

// Problem constants
#define NN 8192
#define FF 128
#define DD 128
#define HH 2
#define ALPHA 0.3f
#define MAXNNZ 1024

typedef float v4f __attribute__((ext_vector_type(4)));

// ---------------------------------------------------------------------------
// Kernel 1: fused prep + sa. Grid 128, 256 threads. Block b handles rows
//   n = b*64 .. b*64+63.
//   Stage 1: c1[h,f] = Wmap[h,f,:].a1w[h,:] (c2 likewise) computed
//            redundantly per block into LDS (Wmap = 128 KB, L2-resident).
//   Stage 2: per-wave (64 lanes, float2/lane): row scores
//            sa1[h,n] = x[n,:].c1[h,:] + a1b[h], sa2p interleaved per node;
//            xsum column partials from the same x loads -> atomicAdd.
// ---------------------------------------------------------------------------
__global__ __launch_bounds__(256) void prep_sa(
    const float* __restrict__ Wmap, const float* __restrict__ a1w,
    const float* __restrict__ a2w, const float* __restrict__ a1b,
    const float* __restrict__ a2b, const float* __restrict__ x,
    float* __restrict__ sa1, float* __restrict__ sa2p, float* __restrict__ xsum) {
  __shared__ float c1s[2 * FF], c2s[2 * FF];
  __shared__ float xsp[4][FF];
  int b = blockIdx.x, t = threadIdx.x;

  // ---- Stage 1: c1/c2 into LDS ----
  {
    int h = t >> 7, f = t & 127;
    const v4f* wrow = (const v4f*)(Wmap + ((size_t)h * FF + f) * DD);
    const v4f* a1 = (const v4f*)(a1w + h * DD);
    const v4f* a2 = (const v4f*)(a2w + h * DD);
    v4f s1 = {0.f, 0.f, 0.f, 0.f}, s2 = {0.f, 0.f, 0.f, 0.f};
    #pragma unroll 8
    for (int d4 = 0; d4 < DD / 4; d4++) {
      v4f wv = wrow[d4];
      s1 += wv * a1[d4];
      s2 += wv * a2[d4];
    }
    c1s[t] = s1.x + s1.y + s1.z + s1.w;
    c2s[t] = s2.x + s2.y + s2.z + s2.w;
  }
  __syncthreads();

  // ---- Stage 2: per-wave row scores + xsum partials ----
  int w = t >> 6, l = t & 63;
  float c10 = c1s[2 * l],      c11 = c1s[2 * l + 1];
  float c1h0 = c1s[FF + 2 * l], c1h1 = c1s[FF + 2 * l + 1];
  float c20 = c2s[2 * l],      c21 = c2s[2 * l + 1];
  float c2h0 = c2s[FF + 2 * l], c2h1 = c2s[FF + 2 * l + 1];
  float b10 = a1b[0], b11 = a1b[1], b20 = a2b[0], b21 = a2b[1];
  float xa0 = 0.f, xa1 = 0.f;
  for (int rr = 0; rr < 16; rr++) {
    int n = b * 64 + w * 16 + rr;
    float2 xv = ((const float2*)(x + (size_t)n * FF))[l];
    xa0 += xv.x;
    xa1 += xv.y;
    float p00 = xv.x * c10 + xv.y * c11;
    float p01 = xv.x * c1h0 + xv.y * c1h1;
    float p10 = xv.x * c20 + xv.y * c21;
    float p11 = xv.x * c2h0 + xv.y * c2h1;
    #pragma unroll
    for (int o = 32; o > 0; o >>= 1) {
      p00 += __shfl_down(p00, o);
      p01 += __shfl_down(p01, o);
      p10 += __shfl_down(p10, o);
      p11 += __shfl_down(p11, o);
    }
    if (l == 0) {
      sa1[n]      = p00 + b10;
      sa1[NN + n] = p01 + b11;
      ((float2*)sa2p)[n] = make_float2(p10 + b20, p11 + b21);
    }
  }
  xsp[w][2 * l]     = xa0;
  xsp[w][2 * l + 1] = xa1;
  __syncthreads();
  if (t < FF) {
    float s = xsp[0][t] + xsp[1][t] + xsp[2][t] + xsp[3][t];
    atomicAdd(&xsum[t], s);   // 128 adds per address total -> negligible
  }
}

// ---------------------------------------------------------------------------
// Kernel 2 (fused stream+gather): one block (256 thr) per row i.
//   Phase A: nontemporal float4-scan of adj row -> compact indices in LDS.
//   Phase B: single pass, 8 edge-groups x 32 lanes, SOFTWARE-PIPELINED:
//            (idx, sa2, x-row) for iteration k+8 are issued before the
//            exp/FMA of iteration k, hiding the L2 gather latency.
//   Epilogue: reduce groups, fold xsum (absorbs colsum), scale 0.5/denom.
// ---------------------------------------------------------------------------
__global__ __launch_bounds__(256) void gat_fused(
    const float* __restrict__ adj, const float* __restrict__ x,
    const float* __restrict__ sa1, const float* __restrict__ sa2p,
    const float* __restrict__ xsum, float* __restrict__ gs) {
  int i = blockIdx.x;
  __shared__ int idxbuf[MAXNNZ];
  __shared__ int cnt;
  __shared__ float esum_sh[8][HH];
  __shared__ v4f vred[HH][8][32];
  int t = threadIdx.x;
  if (t == 0) cnt = 0;
  __syncthreads();

  // ---- Phase A: compact adjacency row ----
  const v4f* arow = (const v4f*)(adj + (size_t)i * NN);
  #pragma unroll
  for (int q = 0; q < 8; q++) {
    int f4 = q * 256 + t;               // 0..2047
    v4f a = __builtin_nontemporal_load(&arow[f4]);
    int j0 = f4 * 4;
    if (a.x != 0.f) { int p = atomicAdd(&cnt, 1); if (p < MAXNNZ) idxbuf[p] = j0; }
    if (a.y != 0.f) { int p = atomicAdd(&cnt, 1); if (p < MAXNNZ) idxbuf[p] = j0 + 1; }
    if (a.z != 0.f) { int p = atomicAdd(&cnt, 1); if (p < MAXNNZ) idxbuf[p] = j0 + 2; }
    if (a.w != 0.f) { int p = atomicAdd(&cnt, 1); if (p < MAXNNZ) idxbuf[p] = j0 + 3; }
  }
  __syncthreads();
  int count = min(cnt, MAXNNZ);

  // ---- Phase B: pipelined score + gather ----
  float s10 = sa1[i];
  float s11 = sa1[NN + i];
  int sub = t & 31;                  // d-group: cols sub*4 .. sub*4+3
  int eg  = t >> 5;                  // edge slot 0..7
  v4f acc0 = {0.f, 0.f, 0.f, 0.f}, acc1 = {0.f, 0.f, 0.f, 0.f};
  float le0 = 0.f, le1 = 0.f;
  const v4f* xb = (const v4f*)x;     // row j = xb[j*32 + sub]
  const float2* s2p = (const float2*)sa2p;

  int j = (eg < count) ? idxbuf[eg] : 0;       // j=0 dummy: valid memory
  float2 s2 = s2p[j];
  v4f xv = xb[(size_t)j * 32 + sub];
  for (int k = eg; k < count; k += 8) {
    int kn = k + 8;
    int jn = (kn < count) ? idxbuf[kn] : 0;
    float2 s2n = s2p[jn];                      // issue next loads first
    v4f xvn = xb[(size_t)jn * 32 + sub];
    float w0 = s10 + s2.x;
    float w1 = s11 + s2.y;
    w0 = (w0 >= 0.f) ? w0 : ALPHA * w0;
    w1 = (w1 >= 0.f) ? w1 : ALPHA * w1;
    float e0 = __expf(w0) - 1.f;
    float e1 = __expf(w1) - 1.f;
    acc0 += e0 * xv;
    acc1 += e1 * xv;
    le0 += e0;
    le1 += e1;
    j = jn; s2 = s2n; xv = xvn;
  }
  vred[0][eg][sub] = acc0;
  vred[1][eg][sub] = acc1;
  if (sub == 0) { esum_sh[eg][0] = le0; esum_sh[eg][1] = le1; }
  __syncthreads();

  // ---- Epilogue ----
  if (t < 64) {
    int h = t >> 5, s = t & 31;
    v4f v = vred[h][0][s];
    #pragma unroll
    for (int e = 1; e < 8; e++) v += vred[h][e][s];
    float sume = 0.f;
    #pragma unroll
    for (int e = 0; e < 8; e++) sume += esum_sh[e][h];
    float inv = 0.5f / ((float)NN + sume);   // 0.5 = head-mean factor
    v4f xs = ((const v4f*)xsum)[s];
    ((v4f*)(gs + (size_t)i * (HH * FF)))[h * 32 + s] = (v + xs) * inv;
  }
}

// ---------------------------------------------------------------------------
// Kernel 3: out = gs @ kern_as_256x128 + 0.5*(bias0+bias1)
//   Grid 512 (16 rows/block) -> 2 blocks/CU, 8 waves/CU: one block's
//   barriers hide under the other's compute. Thread tile 2 rows x 4 cols.
// ---------------------------------------------------------------------------
__global__ __launch_bounds__(256) void out_gemm(
    const float* __restrict__ gs, const float* __restrict__ kern,
    const float* __restrict__ bias, float* __restrict__ out) {
  int row0 = blockIdx.x * 16;
  __shared__ float Bl[64 * 128];    // 32 KB
  __shared__ float Al[16 * 132];    // 8.25 KB (half of K; 132 keeps 16B align)
  const float4* Bg4 = (const float4*)kern;                     // 256x128
  const float4* Ag4 = (const float4*)(gs + (size_t)row0 * 256);
  float4* Bl4 = (float4*)Bl;
  int tid = threadIdx.x;
  int cg = tid & 31;                // cols cg*4..cg*4+3
  int rg = tid >> 5;                // rows rg, rg+8
  v4f acc[2];
  acc[0] = (v4f){0.f, 0.f, 0.f, 0.f};
  acc[1] = (v4f){0.f, 0.f, 0.f, 0.f};

  for (int ka = 0; ka < 2; ka++) {
    __syncthreads();                // prior readers of Al/Bl done
    #pragma unroll
    for (int q = 0; q < 2; q++) {
      int idx = q * 256 + tid;      // 0..511
      int r = idx >> 5, c4 = idx & 31;
      float4 g = Ag4[r * 64 + ka * 32 + c4];
      *(float4*)&Al[r * 132 + c4 * 4] = g;
    }
    #pragma unroll
    for (int kpi = 0; kpi < 2; kpi++) {
      int kp = ka * 2 + kpi;        // 64-row chunk of B
      __syncthreads();              // Al staged + prior Bl readers done
      #pragma unroll
      for (int q = 0; q < 8; q++)
        Bl4[q * 256 + tid] = Bg4[kp * 2048 + q * 256 + tid];
      __syncthreads();
      #pragma unroll 4
      for (int kg = 0; kg < 16; kg++) {
        v4f bv0 = *(const v4f*)&Bl[(kg * 4 + 0) * 128 + cg * 4];
        v4f bv1 = *(const v4f*)&Bl[(kg * 4 + 1) * 128 + cg * 4];
        v4f bv2 = *(const v4f*)&Bl[(kg * 4 + 2) * 128 + cg * 4];
        v4f bv3 = *(const v4f*)&Bl[(kg * 4 + 3) * 128 + cg * 4];
        #pragma unroll
        for (int m = 0; m < 2; m++) {
          v4f a4 = *(const v4f*)&Al[(rg + m * 8) * 132 + kpi * 64 + kg * 4];
          acc[m] += a4.x * bv0;
          acc[m] += a4.y * bv1;
          acc[m] += a4.z * bv2;
          acc[m] += a4.w * bv3;
        }
      }
    }
  }

  #pragma unroll
  for (int m = 0; m < 2; m++) {
    int r = row0 + rg + m * 8;
    v4f b0 = *(const v4f*)&bias[((size_t)0 * NN + r) * DD + cg * 4];
    v4f b1 = *(const v4f*)&bias[((size_t)1 * NN + r) * DD + cg * 4];
    v4f o = acc[m] + 0.5f * (b0 + b1);
    *(v4f*)&out[(size_t)r * DD + cg * 4] = o;
  }
}

// ---------------------------------------------------------------------------
// Launch
// ---------------------------------------------------------------------------
extern "C" void kernel_launch(void* const* d_in, const int* in_sizes, int n_in,
                              void* d_out, int out_size, void* d_ws, size_t ws_size,
                              hipStream_t stream) {
  const float* x    = (const float*)d_in[0];
  const float* adj  = (const float*)d_in[1];
  const float* Wmap = (const float*)d_in[2];
  const float* a1w  = (const float*)d_in[3];
  const float* a1b  = (const float*)d_in[4];
  const float* a2w  = (const float*)d_in[5];
  const float* a2b  = (const float*)d_in[6];
  const float* kern = (const float*)d_in[7];
  const float* bias = (const float*)d_in[8];
  float* out = (float*)d_out;
  float* ws  = (float*)d_ws;

  // workspace layout (floats)
  float* sa1  = ws;                    // 2*8192
  float* sa2p = ws + 16384;            // 2*8192 interleaved
  float* xsum = ws + 32768;            // 128
  float* gs   = ws + 32896;            // 8192*256

  hipMemsetAsync(xsum, 0, FF * sizeof(float), stream);
  prep_sa<<<128, 256, 0, stream>>>(Wmap, a1w, a2w, a1b, a2b, x, sa1, sa2p, xsum);
  gat_fused<<<NN, 256, 0, stream>>>(adj, x, sa1, sa2p, xsum, gs);
  out_gemm<<<NN / 16, 256, 0, stream>>>(gs, kern, bias, out);
}